// Round 9
// baseline (124.833 us; speedup 1.0000x reference)
//
#include <hip/hip_runtime.h>

#define EPS 1e-6f
#define V_LO 0.95f
#define V_HI 1.05f

#define BIN_ELEMS 20480            // 2 floats/node * 20480 = 160 KB LDS (full CU)
#define TPB 1024                   // 16 waves, 1 block/CU
#define MAX_SPLIT 51               // 5 bins * 51 slots = 255 blocks ~ 1/CU
#define BATCH 4

typedef float f32x2 __attribute__((ext_vector_type(2)));

// ---------------------------------------------------------------------------
// Kernel 0: v2[n] = nf[n,0]^2 + nf[n,1]^2  (400 KB table, L2-hot for gathers)
// ---------------------------------------------------------------------------
__global__ void pf_v2_kernel(const float4* __restrict__ nf4,
                             float* __restrict__ v2tab, int n_nodes) {
    int i = blockIdx.x * blockDim.x + threadIdx.x;
    if (i < n_nodes) {
        float4 f = nf4[i];
        v2tab[i] = f.x * f.x + f.y * f.y;
    }
}

// ---------------------------------------------------------------------------
// Kernel 1: edge scan. Block (slot, bin) scans chunk `slot`, 4 edges/thread:
// vector stream loads + 4 independent v2 gathers issued up front (ILP covers
// gather latency at the LDS-capped 16-wave occupancy), fast-rcp flows,
// ds_add_f32 accumulation, nontemporal writeback of the bin slice.
// LDS is a flat float array: node i -> lds[2*i] (p), lds[2*i+1] (q).
// ---------------------------------------------------------------------------
__global__ __launch_bounds__(TPB) void pf_edge_scan(
    const float* __restrict__ v2tab,
    const int* __restrict__ ei,        // (2,E): [0..E)=src, [E..2E)=dst
    const float* __restrict__ probs,
    const float* __restrict__ params,  // (E,2) flat
    float* __restrict__ partial,       // [split][n_nodes*2]
    int n_edges, int n_nodes, int nbins, int per_chunk)
{
    extern __shared__ float lds[];     // 2*BIN_ELEMS floats
    int bin  = blockIdx.x % nbins;
    int slot = blockIdx.x / nbins;
    int node_base = bin * BIN_ELEMS;

    for (int i = threadIdx.x; i < 2 * BIN_ELEMS; i += TPB)
        lds[i] = 0.0f;
    __syncthreads();

    int e0 = slot * per_chunk;                    // per_chunk % 4 == 0
    int e1 = min(e0 + per_chunk, n_edges);

    for (int e = e0 + threadIdx.x * BATCH; e < e1; e += TPB * BATCH) {
        if (e + BATCH <= e1) {
            int4   s4  = *reinterpret_cast<const int4*>(&ei[e]);
            int4   d4  = *reinterpret_cast<const int4*>(&ei[n_edges + e]);
            float4 pb4 = *reinterpret_cast<const float4*>(&probs[e]);
            float4 prA = *reinterpret_cast<const float4*>(&params[(size_t)e * 2]);
            float4 prB = *reinterpret_cast<const float4*>(&params[(size_t)e * 2 + 4]);

            // issue all 4 gathers before any dependent math
            float v2_0 = v2tab[s4.x];
            float v2_1 = v2tab[s4.y];
            float v2_2 = v2tab[s4.z];
            float v2_3 = v2tab[s4.w];

            #pragma unroll
            for (int k = 0; k < BATCH; ++k) {
                int   src  = (k == 0) ? s4.x : (k == 1) ? s4.y : (k == 2) ? s4.z : s4.w;
                int   dst  = (k == 0) ? d4.x : (k == 1) ? d4.y : (k == 2) ? d4.z : d4.w;
                float prob = (k == 0) ? pb4.x : (k == 1) ? pb4.y : (k == 2) ? pb4.z : pb4.w;
                float prx  = (k == 0) ? prA.x : (k == 1) ? prA.z : (k == 2) ? prB.x : prB.z;
                float pry  = (k == 0) ? prA.y : (k == 1) ? prA.w : (k == 2) ? prB.y : prB.w;
                float v2   = (k == 0) ? v2_0 : (k == 1) ? v2_1 : (k == 2) ? v2_2 : v2_3;

                unsigned ls = (unsigned)(src - node_base);
                unsigned ld = (unsigned)(dst - node_base);
                bool cs = ls < (unsigned)BIN_ELEMS;
                bool cd = (ld < (unsigned)BIN_ELEMS) & (src != dst);
                if (cs | cd) {
                    float pe = v2 * prob * __builtin_amdgcn_rcpf(prx + EPS);
                    float qe = v2 * prob * __builtin_amdgcn_rcpf(pry + EPS);
                    if (cs) {
                        atomicAdd(&lds[2 * ls],     pe);   // ds_add_f32
                        atomicAdd(&lds[2 * ls + 1], qe);
                    }
                    if (cd) {
                        atomicAdd(&lds[2 * ld],     pe);
                        atomicAdd(&lds[2 * ld + 1], qe);
                    }
                }
            }
        } else {
            for (int t = e; t < e1; ++t) {          // cold tail, scalar
                int src = ei[t];
                int dst = ei[n_edges + t];
                unsigned ls = (unsigned)(src - node_base);
                unsigned ld = (unsigned)(dst - node_base);
                bool cs = ls < (unsigned)BIN_ELEMS;
                bool cd = (ld < (unsigned)BIN_ELEMS) & (src != dst);
                if (cs | cd) {
                    float v2 = v2tab[src];
                    float pe = v2 * probs[t] * __builtin_amdgcn_rcpf(params[(size_t)t * 2] + EPS);
                    float qe = v2 * probs[t] * __builtin_amdgcn_rcpf(params[(size_t)t * 2 + 1] + EPS);
                    if (cs) { atomicAdd(&lds[2 * ls], pe); atomicAdd(&lds[2 * ls + 1], qe); }
                    if (cd) { atomicAdd(&lds[2 * ld], pe); atomicAdd(&lds[2 * ld + 1], qe); }
                }
            }
        }
    }
    __syncthreads();

    int lim = min(BIN_ELEMS, n_nodes - node_base);
    float* out = partial + (size_t)slot * n_nodes * 2 + (size_t)node_base * 2;
    const f32x2* lds2 = reinterpret_cast<const f32x2*>(lds);
    f32x2* out2 = reinterpret_cast<f32x2*>(out);
    for (int i = threadIdx.x; i < lim; i += TPB)
        __builtin_nontemporal_store(lds2[i], &out2[i]);
}

// ---------------------------------------------------------------------------
// Kernel 2: sum partials per node, loss terms, block-reduce, 1 atomic/block.
// ---------------------------------------------------------------------------
__global__ void pf_node_kernel(const float* __restrict__ nf,
                               const float* __restrict__ partial,
                               float* __restrict__ acc,
                               int n_nodes, int split) {
    int i = blockIdx.x * blockDim.x + threadIdx.x;
    float c = 0.0f;
    if (i < n_nodes) {
        float4 f = *reinterpret_cast<const float4*>(&nf[(size_t)i * 4]);
        float p = f.z, q = f.w;
        const f32x2* pp = reinterpret_cast<const f32x2*>(partial) + i;
        for (int s = 0; s < split; ++s) {
            f32x2 fl = __builtin_nontemporal_load(&pp[(size_t)s * n_nodes]);
            p += fl.x;
            q += fl.y;
        }
        float vmag = sqrtf(f.x * f.x + f.y * f.y);
        float lv = fmaxf(V_LO - vmag, 0.0f);
        float uv = fmaxf(vmag - V_HI, 0.0f);
        c = p * p + q * q + lv * lv + uv * uv;
    }
    #pragma unroll
    for (int off = 32; off > 0; off >>= 1)
        c += __shfl_down(c, off);
    __shared__ float wsum[4];
    int lane = threadIdx.x & 63;
    int wid  = threadIdx.x >> 6;
    if (lane == 0) wsum[wid] = c;
    __syncthreads();
    if (threadIdx.x == 0) {
        float s = 0.0f;
        int nw = blockDim.x >> 6;
        for (int w = 0; w < nw; ++w) s += wsum[w];
        atomicAdd(acc, s);
    }
}

__global__ void pf_finalize_kernel(const float* __restrict__ acc,
                                   float* __restrict__ out,
                                   float inv_n) {
    out[0] = acc[0] * inv_n;
}

extern "C" void kernel_launch(void* const* d_in, const int* in_sizes, int n_in,
                              void* d_out, int out_size, void* d_ws, size_t ws_size,
                              hipStream_t stream) {
    const float* nf     = (const float*)d_in[0];    // (N,4) f32
    const int*   ei     = (const int*)d_in[1];      // (2,E) int
    const float* probs  = (const float*)d_in[2];    // (E,) f32
    const float* params = (const float*)d_in[3];    // (E,2) f32 flat

    int n_nodes = in_sizes[0] / 4;
    int n_edges = in_sizes[2];

    // ws layout: [acc, pad 256B][v2 table: n_nodes f32, pad to 256B][partial]
    float* acc   = (float*)d_ws;
    float* v2tab = (float*)((char*)d_ws + 256);
    size_t v2_bytes = ((size_t)n_nodes * sizeof(float) + 255) & ~(size_t)255;
    float* partial = (float*)((char*)d_ws + 256 + v2_bytes);

    size_t slot_bytes = (size_t)n_nodes * 2 * sizeof(float);
    int split = (int)((ws_size - 256 - v2_bytes) / slot_bytes);
    if (split > MAX_SPLIT) split = MAX_SPLIT;
    if (split < 1) split = 1;

    int nbins = (n_nodes + BIN_ELEMS - 1) / BIN_ELEMS;
    int per_chunk = (n_edges + split - 1) / split;
    per_chunk = (per_chunk + 3) & ~3;               // multiple of BATCH

    size_t lds_bytes = (size_t)(2 * BIN_ELEMS) * sizeof(float);   // 160 KB
    (void)hipFuncSetAttribute((const void*)pf_edge_scan,
                              hipFuncAttributeMaxDynamicSharedMemorySize,
                              (int)lds_bytes);

    (void)hipMemsetAsync(d_ws, 0, 256, stream);     // acc only

    pf_v2_kernel<<<(n_nodes + 255) / 256, 256, 0, stream>>>(
        (const float4*)nf, v2tab, n_nodes);

    pf_edge_scan<<<nbins * split, TPB, lds_bytes, stream>>>(
        v2tab, ei, probs, params, partial, n_edges, n_nodes, nbins, per_chunk);

    int nblocks = (n_nodes + 255) / 256;
    pf_node_kernel<<<nblocks, 256, 0, stream>>>(nf, partial, acc, n_nodes, split);

    pf_finalize_kernel<<<1, 1, 0, stream>>>(acc, (float*)d_out,
                                            1.0f / (float)n_nodes);
}

// Round 10
// 117.084 us; speedup vs baseline: 1.0662x; 1.0662x over previous
//
#include <hip/hip_runtime.h>

#define EPS 1e-6f
#define V_LO 0.95f
#define V_HI 1.05f

#define BIN_ELEMS 20480            // 2 floats/node * 20480 = 160 KB LDS (full CU)
#define TPB 1024                   // 16 waves, 1 block/CU
#define MAX_SPLIT 51               // 5 bins * 51 slots = 255 blocks ~ 1/CU
#define BATCH 4

typedef float f32x2 __attribute__((ext_vector_type(2)));

// ---------------------------------------------------------------------------
// Kernel 0: v2[n] = nf[n,0]^2 + nf[n,1]^2  (400 KB table, L2-hot for gathers)
// ---------------------------------------------------------------------------
__global__ void pf_v2_kernel(const float4* __restrict__ nf4,
                             float* __restrict__ v2tab, int n_nodes) {
    int i = blockIdx.x * blockDim.x + threadIdx.x;
    if (i < n_nodes) {
        float4 f = nf4[i];
        v2tab[i] = f.x * f.x + f.y * f.y;
    }
}

// ---------------------------------------------------------------------------
// Kernel 1: edge scan. Block (slot, bin) scans chunk `slot`, 4 edges/thread
// (vector stream loads). The v2 gather is PREDICATED on bin membership:
// exec-masked lanes generate no TA transactions (round-9 lesson: the
// divergent gather pipe is the bottleneck — unconditional gathers cost 2.8x).
// ds_add_f32 accumulation; nontemporal writeback of the bin slice.
// LDS: node i -> lds[2*i] (p), lds[2*i+1] (q).
// ---------------------------------------------------------------------------
__global__ __launch_bounds__(TPB) void pf_edge_scan(
    const float* __restrict__ v2tab,
    const int* __restrict__ ei,        // (2,E): [0..E)=src, [E..2E)=dst
    const float* __restrict__ probs,
    const float* __restrict__ params,  // (E,2) flat
    float* __restrict__ partial,       // [split][n_nodes*2]
    int n_edges, int n_nodes, int nbins, int per_chunk)
{
    extern __shared__ float lds[];     // 2*BIN_ELEMS floats
    int bin  = blockIdx.x % nbins;
    int slot = blockIdx.x / nbins;
    int node_base = bin * BIN_ELEMS;

    for (int i = threadIdx.x; i < 2 * BIN_ELEMS; i += TPB)
        lds[i] = 0.0f;
    __syncthreads();

    int e0 = slot * per_chunk;                    // per_chunk % 4 == 0
    int e1 = min(e0 + per_chunk, n_edges);

    for (int e = e0 + threadIdx.x * BATCH; e < e1; e += TPB * BATCH) {
        if (e + BATCH <= e1) {
            int4   s4  = *reinterpret_cast<const int4*>(&ei[e]);
            int4   d4  = *reinterpret_cast<const int4*>(&ei[n_edges + e]);
            float4 pb4 = *reinterpret_cast<const float4*>(&probs[e]);
            float4 prA = *reinterpret_cast<const float4*>(&params[(size_t)e * 2]);
            float4 prB = *reinterpret_cast<const float4*>(&params[(size_t)e * 2 + 4]);

            #pragma unroll
            for (int k = 0; k < BATCH; ++k) {
                int   src  = (k == 0) ? s4.x : (k == 1) ? s4.y : (k == 2) ? s4.z : s4.w;
                int   dst  = (k == 0) ? d4.x : (k == 1) ? d4.y : (k == 2) ? d4.z : d4.w;
                float prob = (k == 0) ? pb4.x : (k == 1) ? pb4.y : (k == 2) ? pb4.z : pb4.w;
                float prx  = (k == 0) ? prA.x : (k == 1) ? prA.z : (k == 2) ? prB.x : prB.z;
                float pry  = (k == 0) ? prA.y : (k == 1) ? prA.w : (k == 2) ? prB.y : prB.w;

                unsigned ls = (unsigned)(src - node_base);
                unsigned ld = (unsigned)(dst - node_base);
                bool cs = ls < (unsigned)BIN_ELEMS;
                bool cd = (ld < (unsigned)BIN_ELEMS) & (src != dst);
                if (cs | cd) {
                    float v2 = v2tab[src];        // predicated gather
                    float pe = v2 * prob * __builtin_amdgcn_rcpf(prx + EPS);
                    float qe = v2 * prob * __builtin_amdgcn_rcpf(pry + EPS);
                    if (cs) {
                        atomicAdd(&lds[2 * ls],     pe);   // ds_add_f32
                        atomicAdd(&lds[2 * ls + 1], qe);
                    }
                    if (cd) {
                        atomicAdd(&lds[2 * ld],     pe);
                        atomicAdd(&lds[2 * ld + 1], qe);
                    }
                }
            }
        } else {
            for (int t = e; t < e1; ++t) {          // cold tail, scalar
                int src = ei[t];
                int dst = ei[n_edges + t];
                unsigned ls = (unsigned)(src - node_base);
                unsigned ld = (unsigned)(dst - node_base);
                bool cs = ls < (unsigned)BIN_ELEMS;
                bool cd = (ld < (unsigned)BIN_ELEMS) & (src != dst);
                if (cs | cd) {
                    float v2 = v2tab[src];
                    float pe = v2 * probs[t] * __builtin_amdgcn_rcpf(params[(size_t)t * 2] + EPS);
                    float qe = v2 * probs[t] * __builtin_amdgcn_rcpf(params[(size_t)t * 2 + 1] + EPS);
                    if (cs) { atomicAdd(&lds[2 * ls], pe); atomicAdd(&lds[2 * ls + 1], qe); }
                    if (cd) { atomicAdd(&lds[2 * ld], pe); atomicAdd(&lds[2 * ld + 1], qe); }
                }
            }
        }
    }
    __syncthreads();

    int lim = min(BIN_ELEMS, n_nodes - node_base);
    float* out = partial + (size_t)slot * n_nodes * 2 + (size_t)node_base * 2;
    const f32x2* lds2 = reinterpret_cast<const f32x2*>(lds);
    f32x2* out2 = reinterpret_cast<f32x2*>(out);
    for (int i = threadIdx.x; i < lim; i += TPB)
        __builtin_nontemporal_store(lds2[i], &out2[i]);
}

// ---------------------------------------------------------------------------
// Kernel 2: sum partials per node, loss terms, block-reduce, 1 atomic/block.
// ---------------------------------------------------------------------------
__global__ void pf_node_kernel(const float* __restrict__ nf,
                               const float* __restrict__ partial,
                               float* __restrict__ acc,
                               int n_nodes, int split) {
    int i = blockIdx.x * blockDim.x + threadIdx.x;
    float c = 0.0f;
    if (i < n_nodes) {
        float4 f = *reinterpret_cast<const float4*>(&nf[(size_t)i * 4]);
        float p = f.z, q = f.w;
        const f32x2* pp = reinterpret_cast<const f32x2*>(partial) + i;
        for (int s = 0; s < split; ++s) {
            f32x2 fl = __builtin_nontemporal_load(&pp[(size_t)s * n_nodes]);
            p += fl.x;
            q += fl.y;
        }
        float vmag = sqrtf(f.x * f.x + f.y * f.y);
        float lv = fmaxf(V_LO - vmag, 0.0f);
        float uv = fmaxf(vmag - V_HI, 0.0f);
        c = p * p + q * q + lv * lv + uv * uv;
    }
    #pragma unroll
    for (int off = 32; off > 0; off >>= 1)
        c += __shfl_down(c, off);
    __shared__ float wsum[4];
    int lane = threadIdx.x & 63;
    int wid  = threadIdx.x >> 6;
    if (lane == 0) wsum[wid] = c;
    __syncthreads();
    if (threadIdx.x == 0) {
        float s = 0.0f;
        int nw = blockDim.x >> 6;
        for (int w = 0; w < nw; ++w) s += wsum[w];
        atomicAdd(acc, s);
    }
}

__global__ void pf_finalize_kernel(const float* __restrict__ acc,
                                   float* __restrict__ out,
                                   float inv_n) {
    out[0] = acc[0] * inv_n;
}

extern "C" void kernel_launch(void* const* d_in, const int* in_sizes, int n_in,
                              void* d_out, int out_size, void* d_ws, size_t ws_size,
                              hipStream_t stream) {
    const float* nf     = (const float*)d_in[0];    // (N,4) f32
    const int*   ei     = (const int*)d_in[1];      // (2,E) int
    const float* probs  = (const float*)d_in[2];    // (E,) f32
    const float* params = (const float*)d_in[3];    // (E,2) f32 flat

    int n_nodes = in_sizes[0] / 4;
    int n_edges = in_sizes[2];

    // ws layout: [acc, pad 256B][v2 table: n_nodes f32, pad to 256B][partial]
    float* acc   = (float*)d_ws;
    float* v2tab = (float*)((char*)d_ws + 256);
    size_t v2_bytes = ((size_t)n_nodes * sizeof(float) + 255) & ~(size_t)255;
    float* partial = (float*)((char*)d_ws + 256 + v2_bytes);

    size_t slot_bytes = (size_t)n_nodes * 2 * sizeof(float);
    int split = (int)((ws_size - 256 - v2_bytes) / slot_bytes);
    if (split > MAX_SPLIT) split = MAX_SPLIT;
    if (split < 1) split = 1;

    int nbins = (n_nodes + BIN_ELEMS - 1) / BIN_ELEMS;
    int per_chunk = (n_edges + split - 1) / split;
    per_chunk = (per_chunk + 3) & ~3;               // multiple of BATCH

    size_t lds_bytes = (size_t)(2 * BIN_ELEMS) * sizeof(float);   // 160 KB
    (void)hipFuncSetAttribute((const void*)pf_edge_scan,
                              hipFuncAttributeMaxDynamicSharedMemorySize,
                              (int)lds_bytes);

    (void)hipMemsetAsync(d_ws, 0, 256, stream);     // acc only

    pf_v2_kernel<<<(n_nodes + 255) / 256, 256, 0, stream>>>(
        (const float4*)nf, v2tab, n_nodes);

    pf_edge_scan<<<nbins * split, TPB, lds_bytes, stream>>>(
        v2tab, ei, probs, params, partial, n_edges, n_nodes, nbins, per_chunk);

    int nblocks = (n_nodes + 255) / 256;
    pf_node_kernel<<<nblocks, 256, 0, stream>>>(nf, partial, acc, n_nodes, split);

    pf_finalize_kernel<<<1, 1, 0, stream>>>(acc, (float*)d_out,
                                            1.0f / (float)n_nodes);
}